// Round 7
// baseline (110.995 us; speedup 1.0000x reference)
//
#include <hip/hip_runtime.h>
#include <math.h>

// Problem constants (from reference)
#define BB 4
#define HH 512
#define WW 512
#define CC 32      // channels; 32 floats = 8 float4 = 128 B per point
#define HO 256
#define WO 256

#define MAXW 56    // staged slots per wave (avg occupancy ~24, +7.6 sigma)

// Fill index grid with zeros (0 == empty). int4-vectorized.
__global__ void fill_zero_kernel(int4* __restrict__ g, int n4) {
    int i = blockIdx.x * blockDim.x + threadIdx.x;
    if (i < n4) g[i] = make_int4(0, 0, 0, 0);
}

// Scatter point index+1 into dense (B,H,W) int grid.
__global__ void scatter_idx_kernel(const int* __restrict__ coors,
                                   int* __restrict__ grid, int n) {
    int i = blockIdx.x * blockDim.x + threadIdx.x;
    if (i >= n) return;
    int b = coors[i * 3 + 0];
    int y = coors[i * 3 + 1];
    int x = coors[i * 3 + 2];
    grid[((size_t)b * HH + y) * WW + x] = i + 1;
}

// Wave-autonomous pool: each wave owns 8 ox x 2 oy x 8 cg outputs
// (window 5 rows x 17 cols = 85 grid cells). Per wave, NO barriers:
//   1) read 85 grid cells from global (<=2 loads/lane)
//   2) ballot+popc prefix compaction (no atomics)
//   3) stage ~24 occupied feature rows into a PRIVATE LDS region
//   4) 15 LDS window reads/lane, fmax-reduce, 2 coalesced stores
// Cross-wave latency hiding comes from 20 unsynchronized waves/CU.
__global__ void __launch_bounds__(256)
pool_kernel(const float4* __restrict__ feat,   // N x 8 float4
            const int* __restrict__ grid,      // B*H*W
            float4* __restrict__ out) {        // B*HO*WO x 8 float4
    // blockIdx.x: [b(2b) | t(7b) | ox_tile(3b)],  t = oy pair index 0..127
    int ox_base = (blockIdx.x & 7) * 32;
    int t       = (blockIdx.x >> 3) & 127;
    int b       = blockIdx.x >> 10;

    int tid  = threadIdx.x;
    int w    = tid >> 6;        // wave 0..3
    int lane = tid & 63;
    int cg   = lane & 7;        // channel group 0..7
    int pl   = lane >> 3;       // local position 0..7

    int iy0  = 4 * t - 1;               // first of 5 input rows
    int gx0w = 2 * (ox_base + w * 8) - 1; // wave's first input col
    const int* gb = grid + (size_t)b * (HH * WW);

    __shared__ float4 sfeat[4][MAXW * 8];   // per-wave, swizzled
    __shared__ int    srcidx[4][MAXW];
    __shared__ int    smap[4][5 * 17];      // 0=empty, s+1=slot, -(i+1)=direct

    unsigned long long lt = (1ull << lane) - 1ull;

    // ---- 1+2) grid read + ballot compaction (2 rounds: cells 0..63, 64..84)
    // round 0: cell e0 = lane
    int r0 = lane / 17;         // 0..3
    int c0 = lane - r0 * 17;
    int iyA = iy0 + r0, gxA = gx0w + c0;
    int v0 = 0;
    if ((unsigned)iyA < (unsigned)HH && (unsigned)gxA < (unsigned)WW)
        v0 = gb[iyA * WW + gxA];
    unsigned long long m0 = __ballot(v0 != 0);
    int s0 = (int)__popcll(m0 & lt);
    int base1 = (int)__popcll(m0);
    {
        int m = 0;
        if (v0 != 0) {
            if (s0 < MAXW) { srcidx[w][s0] = v0 - 1; m = s0 + 1; }
            else           { m = -v0; }
        }
        smap[w][lane] = m;
    }
    // round 1: cell e1 = 64 + lane (lane < 21)
    int e1 = 64 + lane;
    int r1 = e1 / 17;           // 3..4
    int c1 = e1 - r1 * 17;
    int iyB = iy0 + r1, gxB = gx0w + c1;
    int v1 = 0;
    if (lane < 21 && (unsigned)iyB < (unsigned)HH && (unsigned)gxB < (unsigned)WW)
        v1 = gb[iyB * WW + gxB];
    unsigned long long m1 = __ballot(v1 != 0);
    int s1 = base1 + (int)__popcll(m1 & lt);
    if (lane < 21) {
        int m = 0;
        if (v1 != 0) {
            if (s1 < MAXW) { srcidx[w][s1] = v1 - 1; m = s1 + 1; }
            else           { m = -v1; }
        }
        smap[w][e1] = m;
    }
    int cnt = base1 + (int)__popcll(m1);
    if (cnt > MAXW) cnt = MAXW;

    // ---- 3) stage occupied rows into private LDS (8 lanes per row)
    for (int s = pl; s < cnt; s += 8) {
        sfeat[w][(s << 3) + ((cg + s) & 7)] = feat[(size_t)srcidx[w][s] * 8 + cg];
    }

    // ---- 4) window reduce from LDS (wave-internal waitcnt ordering only)
    int lc = 2 * pl;            // window cols lc..lc+2
    int mm[15];
#pragma unroll
    for (int r = 0; r < 5; ++r)
#pragma unroll
        for (int dx = 0; dx < 3; ++dx)
            mm[r * 3 + dx] = smap[w][r * 17 + lc + dx];

    float4 f[15];
#pragma unroll
    for (int k = 0; k < 15; ++k) {
        int s = mm[k] > 0 ? mm[k] - 1 : 0;
        f[k] = sfeat[w][(s << 3) + ((cg + s) & 7)];
    }
    // rare overflow fixup: direct global gather
#pragma unroll
    for (int k = 0; k < 15; ++k) {
        if (mm[k] < 0) f[k] = feat[(size_t)(-mm[k] - 1) * 8 + cg];
    }

    const float NEG = -INFINITY;
    float4 acc0 = make_float4(NEG, NEG, NEG, NEG);   // rows 0..2
    float4 acc1 = make_float4(NEG, NEG, NEG, NEG);   // rows 2..4
#pragma unroll
    for (int k = 0; k < 15; ++k) {
        bool ok = mm[k] != 0;
        float fx = ok ? f[k].x : NEG;
        float fy = ok ? f[k].y : NEG;
        float fz = ok ? f[k].z : NEG;
        float fw = ok ? f[k].w : NEG;
        if (k < 9) {            // rows 0,1,2
            acc0.x = fmaxf(acc0.x, fx);
            acc0.y = fmaxf(acc0.y, fy);
            acc0.z = fmaxf(acc0.z, fz);
            acc0.w = fmaxf(acc0.w, fw);
        }
        if (k >= 6) {           // rows 2,3,4
            acc1.x = fmaxf(acc1.x, fx);
            acc1.y = fmaxf(acc1.y, fy);
            acc1.z = fmaxf(acc1.z, fz);
            acc1.w = fmaxf(acc1.w, fw);
        }
    }

    acc0.x = isinf(acc0.x) ? 0.0f : acc0.x;
    acc0.y = isinf(acc0.y) ? 0.0f : acc0.y;
    acc0.z = isinf(acc0.z) ? 0.0f : acc0.z;
    acc0.w = isinf(acc0.w) ? 0.0f : acc0.w;
    acc1.x = isinf(acc1.x) ? 0.0f : acc1.x;
    acc1.y = isinf(acc1.y) ? 0.0f : acc1.y;
    acc1.z = isinf(acc1.z) ? 0.0f : acc1.z;
    acc1.w = isinf(acc1.w) ? 0.0f : acc1.w;

    int oy0 = 2 * t;
    size_t pos0 = ((size_t)(b * HO + oy0) * WO + ox_base + w * 8 + pl);
    out[pos0 * 8 + cg]        = acc0;
    out[(pos0 + WO) * 8 + cg] = acc1;
}

extern "C" void kernel_launch(void* const* d_in, const int* in_sizes, int n_in,
                              void* d_out, int out_size, void* d_ws, size_t ws_size,
                              hipStream_t stream) {
    const float* features = (const float*)d_in[0];   // N x 32 fp32
    const int*   coors    = (const int*)d_in[1];     // N x 3 int32
    int n = in_sizes[0] / CC;                        // N = 300000

    int* grid = (int*)d_ws;                          // B*H*W int32 = 4 MiB

    // 1) zero the index grid (0xAA-poisoned every timed call)
    {
        int n4 = (BB * HH * WW) / 4;                 // 262144 int4
        int blk = 256, grd = (n4 + blk - 1) / blk;
        fill_zero_kernel<<<grd, blk, 0, stream>>>((int4*)grid, n4);
    }
    // 2) scatter indices
    {
        int blk = 256, grd = (n + blk - 1) / blk;
        scatter_idx_kernel<<<grd, blk, 0, stream>>>(coors, grid, n);
    }
    // 3) pool: 4096 blocks (4 independent waves; 8 ox x 2 oy x 8 cg each)
    {
        int grd = BB * (HO / 2) * (WO / 32);         // 4096
        pool_kernel<<<grd, 256, 0, stream>>>((const float4*)features, grid,
                                             (float4*)d_out);
    }
}

// Round 8
// 107.022 us; speedup vs baseline: 1.0371x; 1.0371x over previous
//
#include <hip/hip_runtime.h>
#include <math.h>

// Problem constants (from reference)
#define BB 4
#define HH 512
#define WW 512
#define CC 32      // channels; 32 floats = 8 float4 = 128 B per point
#define HO 256
#define WO 256

#define MAXOCC 96  // staged slots/block; window 3x65=195 cells, mean occ ~56 (+6.3 sigma)

// Fill index grid with zeros (0 == empty). int4-vectorized.
__global__ void fill_zero_kernel(int4* __restrict__ g, int n4) {
    int i = blockIdx.x * blockDim.x + threadIdx.x;
    if (i < n4) g[i] = make_int4(0, 0, 0, 0);
}

// Scatter point index+1 into dense (B,H,W) int grid.
__global__ void scatter_idx_kernel(const int* __restrict__ coors,
                                   int* __restrict__ grid, int n) {
    int i = blockIdx.x * blockDim.x + threadIdx.x;
    if (i >= n) return;
    int b = coors[i * 3 + 0];
    int y = coors[i * 3 + 1];
    int x = coors[i * 3 + 2];
    grid[((size_t)b * HH + y) * WW + x] = i + 1;
}

// Block = 32 ox x 1 oy x 8 cg. Window = 3 rows x 65 cols = 195 cells.
// Pass A: coalesced grid load + per-WAVE ballot compaction (1 LDS atomic/wave).
// Pass B: stage each occupied feature row into LDS once (swizzled, conflict-free).
// Pass C: row-loop reduce from LDS (low VGPR), 1 coalesced store.
// Tuned for max occupancy: ~45 VGPR, 13.4 KB LDS -> 8 blocks/CU (32 waves).
__global__ void __launch_bounds__(256, 8)
pool_kernel(const float4* __restrict__ feat,   // N x 8 float4
            const int* __restrict__ grid,      // B*H*W
            float4* __restrict__ out) {        // B*HO*WO x 8 float4
    // blockIdx.x: [b(2b) | oy(8b) | ox_tile(3b)]
    int ox_base = (blockIdx.x & 7) * 32;
    int oy      = (blockIdx.x >> 3) & (HO - 1);
    int b       = blockIdx.x >> 11;

    int tid  = threadIdx.x;
    int lane = tid & 63;
    int cg   = tid & 7;         // channel group 0..7
    int p    = tid >> 3;        // local position 0..31

    int iy0 = 2 * oy - 1;
    int gx0 = 2 * ox_base - 1;
    const int* gb = grid + (size_t)b * (HH * WW);

    __shared__ int    cnt;
    __shared__ int    smap[3 * 65];        // 0=empty, s+1=slot, -(i+1)=direct
    __shared__ int    srcidx[MAXOCC];
    __shared__ float4 sfeat[MAXOCC * 8];   // swizzled: [s*8 + ((cg+s)&7)]

    if (tid == 0) cnt = 0;
    __syncthreads();

    // ---- Pass A: grid load + per-wave ballot compaction (cells 0..194)
    {
        int v = 0;
        if (tid < 195) {
            int r = tid / 65;
            int c = tid - r * 65;
            int iy = iy0 + r;
            int gx = gx0 + c;
            if ((unsigned)iy < (unsigned)HH && (unsigned)gx < (unsigned)WW)
                v = gb[iy * WW + gx];
        }
        unsigned long long mask = __ballot(v != 0);
        int nz = (int)__popcll(mask);
        int base = 0;
        if (lane == 0 && nz) base = atomicAdd(&cnt, nz);
        base = __shfl(base, 0);
        int prefix = (int)__popcll(mask & ((1ull << lane) - 1ull));
        if (tid < 195) {
            int m = 0;
            if (v != 0) {
                int s = base + prefix;
                if (s < MAXOCC) { srcidx[s] = v - 1; m = s + 1; }
                else            { m = -v; }        // overflow: direct gather
            }
            smap[tid] = m;
        }
    }
    __syncthreads();

    // ---- Pass B: cooperative staging (8 lanes per row, 128 B contiguous)
    int total = cnt < MAXOCC ? cnt : MAXOCC;
    for (int s = (tid >> 3); s < total; s += 32)
        sfeat[(s << 3) + ((cg + s) & 7)] = feat[(size_t)srcidx[s] * 8 + cg];
    __syncthreads();

    // ---- Pass C: row-loop window reduce (keeps <=3 payloads live)
    int lc = 2 * p;             // window cols lc..lc+2
    const float NEG = -INFINITY;
    float4 acc = make_float4(NEG, NEG, NEG, NEG);
#pragma unroll
    for (int r = 0; r < 3; ++r) {
        int m0 = smap[r * 65 + lc + 0];
        int m1 = smap[r * 65 + lc + 1];
        int m2 = smap[r * 65 + lc + 2];
        int s0 = m0 > 0 ? m0 - 1 : 0;
        int s1 = m1 > 0 ? m1 - 1 : 0;
        int s2 = m2 > 0 ? m2 - 1 : 0;
        float4 f0 = sfeat[(s0 << 3) + ((cg + s0) & 7)];
        float4 f1 = sfeat[(s1 << 3) + ((cg + s1) & 7)];
        float4 f2 = sfeat[(s2 << 3) + ((cg + s2) & 7)];
        if (m0 < 0) f0 = feat[(size_t)(-m0 - 1) * 8 + cg];   // rare overflow
        if (m1 < 0) f1 = feat[(size_t)(-m1 - 1) * 8 + cg];
        if (m2 < 0) f2 = feat[(size_t)(-m2 - 1) * 8 + cg];
        acc.x = fmaxf(acc.x, m0 != 0 ? f0.x : NEG);
        acc.y = fmaxf(acc.y, m0 != 0 ? f0.y : NEG);
        acc.z = fmaxf(acc.z, m0 != 0 ? f0.z : NEG);
        acc.w = fmaxf(acc.w, m0 != 0 ? f0.w : NEG);
        acc.x = fmaxf(acc.x, m1 != 0 ? f1.x : NEG);
        acc.y = fmaxf(acc.y, m1 != 0 ? f1.y : NEG);
        acc.z = fmaxf(acc.z, m1 != 0 ? f1.z : NEG);
        acc.w = fmaxf(acc.w, m1 != 0 ? f1.w : NEG);
        acc.x = fmaxf(acc.x, m2 != 0 ? f2.x : NEG);
        acc.y = fmaxf(acc.y, m2 != 0 ? f2.y : NEG);
        acc.z = fmaxf(acc.z, m2 != 0 ? f2.z : NEG);
        acc.w = fmaxf(acc.w, m2 != 0 ? f2.w : NEG);
    }

    acc.x = isinf(acc.x) ? 0.0f : acc.x;
    acc.y = isinf(acc.y) ? 0.0f : acc.y;
    acc.z = isinf(acc.z) ? 0.0f : acc.z;
    acc.w = isinf(acc.w) ? 0.0f : acc.w;

    size_t pos = ((size_t)(b * HO + oy) * WO + ox_base + p);
    out[pos * 8 + cg] = acc;
}

extern "C" void kernel_launch(void* const* d_in, const int* in_sizes, int n_in,
                              void* d_out, int out_size, void* d_ws, size_t ws_size,
                              hipStream_t stream) {
    const float* features = (const float*)d_in[0];   // N x 32 fp32
    const int*   coors    = (const int*)d_in[1];     // N x 3 int32
    int n = in_sizes[0] / CC;                        // N = 300000

    int* grid = (int*)d_ws;                          // B*H*W int32 = 4 MiB

    // 1) zero the index grid (0xAA-poisoned every timed call)
    {
        int n4 = (BB * HH * WW) / 4;                 // 262144 int4
        int blk = 256, grd = (n4 + blk - 1) / blk;
        fill_zero_kernel<<<grd, blk, 0, stream>>>((int4*)grid, n4);
    }
    // 2) scatter indices
    {
        int blk = 256, grd = (n + blk - 1) / blk;
        scatter_idx_kernel<<<grd, blk, 0, stream>>>(coors, grid, n);
    }
    // 3) pool: 8192 blocks (32 ox x 1 oy x 8 cg per block), 8 blocks/CU
    {
        int grd = BB * HO * (WO / 32);               // 8192
        pool_kernel<<<grd, 256, 0, stream>>>((const float4*)features, grid,
                                             (float4*)d_out);
    }
}

// Round 9
// 105.786 us; speedup vs baseline: 1.0492x; 1.0117x over previous
//
#include <hip/hip_runtime.h>
#include <math.h>

// Problem constants (from reference)
#define BB 4
#define HH 512
#define WW 512
#define CC 32      // channels; 32 floats = 8 float4 = 128 B per point
#define HO 256
#define WO 256

#define MAXOCC 96   // slots incl sentinel slot 0; real slots 1..95
#define OVFCAP 100  // max overflow cells = 195 - 95

// Fill index grid with zeros (0 == empty). int4-vectorized.
__global__ void fill_zero_kernel(int4* __restrict__ g, int n4) {
    int i = blockIdx.x * blockDim.x + threadIdx.x;
    if (i < n4) g[i] = make_int4(0, 0, 0, 0);
}

// Scatter point index+1 into dense (B,H,W) int grid.
__global__ void scatter_idx_kernel(const int* __restrict__ coors,
                                   int* __restrict__ grid, int n) {
    int i = blockIdx.x * blockDim.x + threadIdx.x;
    if (i >= n) return;
    int b = coors[i * 3 + 0];
    int y = coors[i * 3 + 1];
    int x = coors[i * 3 + 2];
    grid[((size_t)b * HH + y) * WW + x] = i + 1;
}

// Block = 32 ox x 1 oy x 8 cg. Window = 3 rows x 65 cols = 195 cells.
// Slot 0 of sfeat is a -inf SENTINEL row; empty cells map to slot 0, so the
// hot pass is 9 LDS reads + 36 fmax with NO compares/cndmask. Overflow
// (cnt>95, ~1e-6 probability) handled in a block-uniform fixup branch.
__global__ void __launch_bounds__(256, 8)
pool_kernel(const float4* __restrict__ feat,   // N x 8 float4
            const int* __restrict__ grid,      // B*H*W
            float4* __restrict__ out) {        // B*HO*WO x 8 float4
    // blockIdx.x: [b(2b) | oy(8b) | ox_tile(3b)]
    int ox_base = (blockIdx.x & 7) * 32;
    int oy      = (blockIdx.x >> 3) & (HO - 1);
    int b       = blockIdx.x >> 11;

    int tid  = threadIdx.x;
    int lane = tid & 63;
    int cg   = tid & 7;         // channel group 0..7
    int p    = tid >> 3;        // local position 0..31

    int iy0 = 2 * oy - 1;
    int gx0 = 2 * ox_base - 1;
    const int* gb = grid + (size_t)b * (HH * WW);

    __shared__ int    cnt;
    __shared__ int    smap[3 * 65];        // slot index; 0 = empty/sentinel
    __shared__ int    srcidx[MAXOCC];      // slot -> point index (1..95)
    __shared__ float4 sfeat[MAXOCC * 8];   // swizzled: [s*8 + ((cg+s)&7)]
    __shared__ int    ovf_c[OVFCAP];       // overflow cell id
    __shared__ int    ovf_i[OVFCAP];       // overflow point index

    const float NEG = -INFINITY;
    if (tid == 0) cnt = 0;
    if (tid < 8) sfeat[tid] = make_float4(NEG, NEG, NEG, NEG);  // sentinel s=0
    __syncthreads();

    // ---- Pass A: grid load + per-wave ballot compaction (cells 0..194)
    {
        int v = 0;
        if (tid < 195) {
            int r = tid / 65;
            int c = tid - r * 65;
            int iy = iy0 + r;
            int gx = gx0 + c;
            if ((unsigned)iy < (unsigned)HH && (unsigned)gx < (unsigned)WW)
                v = gb[iy * WW + gx];
        }
        unsigned long long mask = __ballot(v != 0);
        int nz = (int)__popcll(mask);
        int base = 0;
        if (lane == 0 && nz) base = atomicAdd(&cnt, nz);
        base = __shfl(base, 0);
        int s = 1 + base + (int)__popcll(mask & ((1ull << lane) - 1ull));
        if (tid < 195) {
            int m = 0;
            if (v != 0) {
                if (s < MAXOCC) { srcidx[s] = v - 1; m = s; }
                else {
                    int o = s - MAXOCC;          // 0..99
                    ovf_c[o] = tid;
                    ovf_i[o] = v - 1;
                }
            }
            smap[tid] = m;
        }
    }
    __syncthreads();

    // ---- Pass B: cooperative staging of slots 1..min(cnt,95)
    int hi = cnt < (MAXOCC - 1) ? cnt : (MAXOCC - 1);
    for (int s = 1 + (tid >> 3); s <= hi; s += 32)
        sfeat[(s << 3) + ((cg + s) & 7)] = feat[(size_t)srcidx[s] * 8 + cg];
    __syncthreads();

    // ---- Pass C: pure loads + fmax (empty -> sentinel -inf row)
    int lc = 2 * p;             // window cols lc..lc+2
    float4 acc = make_float4(NEG, NEG, NEG, NEG);
#pragma unroll
    for (int r = 0; r < 3; ++r) {
        int m0 = smap[r * 65 + lc + 0];
        int m1 = smap[r * 65 + lc + 1];
        int m2 = smap[r * 65 + lc + 2];
        float4 f0 = sfeat[(m0 << 3) + ((cg + m0) & 7)];
        float4 f1 = sfeat[(m1 << 3) + ((cg + m1) & 7)];
        float4 f2 = sfeat[(m2 << 3) + ((cg + m2) & 7)];
        acc.x = fmaxf(fmaxf(acc.x, f0.x), fmaxf(f1.x, f2.x));
        acc.y = fmaxf(fmaxf(acc.y, f0.y), fmaxf(f1.y, f2.y));
        acc.z = fmaxf(fmaxf(acc.z, f0.z), fmaxf(f1.z, f2.z));
        acc.w = fmaxf(fmaxf(acc.w, f0.w), fmaxf(f1.w, f2.w));
    }

    // ---- block-uniform overflow fixup (taken with prob ~1e-6)
    if (cnt >= MAXOCC) {
        int novf = cnt - (MAXOCC - 1);
        if (novf > OVFCAP) novf = OVFCAP;
        for (int o = 0; o < novf; ++o) {
            int cell = ovf_c[o];
            int c = cell % 65;
            if (c >= lc && c <= lc + 2) {       // this output's window
                float4 fv = feat[(size_t)ovf_i[o] * 8 + cg];
                acc.x = fmaxf(acc.x, fv.x);
                acc.y = fmaxf(acc.y, fv.y);
                acc.z = fmaxf(acc.z, fv.z);
                acc.w = fmaxf(acc.w, fv.w);
            }
        }
    }

    acc.x = isinf(acc.x) ? 0.0f : acc.x;
    acc.y = isinf(acc.y) ? 0.0f : acc.y;
    acc.z = isinf(acc.z) ? 0.0f : acc.z;
    acc.w = isinf(acc.w) ? 0.0f : acc.w;

    size_t pos = ((size_t)(b * HO + oy) * WO + ox_base + p);
    out[pos * 8 + cg] = acc;
}

extern "C" void kernel_launch(void* const* d_in, const int* in_sizes, int n_in,
                              void* d_out, int out_size, void* d_ws, size_t ws_size,
                              hipStream_t stream) {
    const float* features = (const float*)d_in[0];   // N x 32 fp32
    const int*   coors    = (const int*)d_in[1];     // N x 3 int32
    int n = in_sizes[0] / CC;                        // N = 300000

    int* grid = (int*)d_ws;                          // B*H*W int32 = 4 MiB

    // 1) zero the index grid (0xAA-poisoned every timed call)
    {
        int n4 = (BB * HH * WW) / 4;                 // 262144 int4
        int blk = 256, grd = (n4 + blk - 1) / blk;
        fill_zero_kernel<<<grd, blk, 0, stream>>>((int4*)grid, n4);
    }
    // 2) scatter indices
    {
        int blk = 256, grd = (n + blk - 1) / blk;
        scatter_idx_kernel<<<grd, blk, 0, stream>>>(coors, grid, n);
    }
    // 3) pool: 8192 blocks (32 ox x 1 oy x 8 cg per block), 8 blocks/CU
    {
        int grd = BB * HO * (WO / 32);               // 8192
        pool_kernel<<<grd, 256, 0, stream>>>((const float4*)features, grid,
                                             (float4*)d_out);
    }
}